// Round 4
// baseline (1062.427 us; speedup 1.0000x reference)
//
#include <hip/hip_runtime.h>
#include <math.h>

// Problem constants (match reference)
#define Bb   256
#define Tt   512
#define Vv   50000
#define Ee   300
#define Hh   128
#define G4   512          // 4*H
#define EPS  1e-12f
#define FBIAS 1.0f

typedef _Float16 half8 __attribute__((ext_vector_type(8)));
typedef float    f32x4 __attribute__((ext_vector_type(4)));

// ---------------------------------------------------------------------------
// Cross-lane helpers (DPP-only reductions)
// ---------------------------------------------------------------------------
template <int CTRL>
__device__ inline float dpp_mov(float v) {
    return __int_as_float(
        __builtin_amdgcn_update_dpp(0, __float_as_int(v), CTRL, 0xF, 0xF, true));
}
// sum over each 16-lane group
__device__ inline float red16(float v) {
    v += dpp_mov<0xB1>(v);    // quad_perm [1,0,3,2]
    v += dpp_mov<0x4E>(v);    // quad_perm [2,3,0,1]
    v += dpp_mov<0x141>(v);   // row_half_mirror
    v += dpp_mov<0x140>(v);   // row_mirror
    return v;
}
// sum over all 64 lanes, result broadcast via readlane (pure VALU, no LDS)
__device__ inline float red64b(float v) {
    v = red16(v);
    v += dpp_mov<0x142>(v);   // row_bcast15: lane15->16..31, lane47->48..63
    v += dpp_mov<0x143>(v);   // row_bcast31: lane31->32..63  => lane63 = total
    return __int_as_float(__builtin_amdgcn_readlane(__float_as_int(v), 63));
}

// barrier that drains only LDS counters (global prefetches float across)
__device__ inline void lds_barrier() {
    __builtin_amdgcn_sched_barrier(0);
    asm volatile("s_waitcnt lgkmcnt(0)" ::: "memory");
    __builtin_amdgcn_sched_barrier(0);
    __builtin_amdgcn_s_barrier();
    __builtin_amdgcn_sched_barrier(0);
}

__device__ inline float sigm(float v) {
    return __fdividef(1.0f, 1.0f + __expf(-v));
}

// ---------------------------------------------------------------------------
// Phase 1: P[v,:] = embed[v,:] @ W[0:E,:] via f16 MFMA.
// 256 blocks x 512 thr (8 waves). Wave w owns cols w*64..w*64+63 (4 tt x 10 ks
// B-fragments resident in VGPRs). embed staged per 32-row tile as f16 in LDS
// (row-major 640B rows, XOR-swizzled), K padded 300->320 with zeros.
// ---------------------------------------------------------------------------
#define PROJ_TILES ((Vv + 31) / 32)

__global__ __launch_bounds__(512, 2) void embed_proj_mfma(
    const float* __restrict__ embed,   // [V, E]
    const float* __restrict__ W,       // [E+H, 4H]
    float* __restrict__ P)             // [V, 4H]
{
    __shared__ __align__(16) _Float16 A[32 * 320];   // 20 KB

    const int tid  = threadIdx.x;
    const int wv   = tid >> 6;
    const int lane = tid & 63;
    const int p16  = lane & 15;
    const int gq   = lane >> 4;

    // B-fragments: col = wv*64 + tt*16 + p16 ; k = ks*32 + gq*8 + j
    half8 bf[4][10];
    #pragma unroll
    for (int tt = 0; tt < 4; ++tt) {
        #pragma unroll
        for (int ks = 0; ks < 10; ++ks) {
            half8 h;
            #pragma unroll
            for (int j = 0; j < 8; ++j) {
                int k = ks * 32 + gq * 8 + j;
                h[j] = (k < Ee)
                     ? (_Float16)W[(size_t)k * G4 + wv * 64 + tt * 16 + p16]
                     : (_Float16)0.f;
            }
            bf[tt][ks] = h;
        }
    }

    char* const Ab = (char*)A;
    // zero the k-pad [300,320) once (stage loop never overwrites it)
    for (int i = tid; i < 32 * 10; i += 512) {
        int row = i / 10, m = i - row * 10;
        *(uint*)(Ab + ((row * 640 + 600 + m * 4) ^ ((row & 7) << 4))) = 0u;
    }
    __syncthreads();

    for (int mtile = blockIdx.x; mtile < PROJ_TILES; mtile += gridDim.x) {
        const int r0 = mtile * 32;

        // stage A-tile: 32 rows x 75 float4 (=300 f32), cvt to f16
        for (int i = tid; i < 32 * 75; i += 512) {
            int row = i / 75, k4 = i - row * 75;
            int grow = r0 + row;
            float4 v = (grow < Vv) ? *(const float4*)&embed[(size_t)grow * Ee + k4 * 4]
                                   : (float4){0.f, 0.f, 0.f, 0.f};
            union { _Float16 h[4]; uint2 u; } pk;
            pk.h[0] = (_Float16)v.x; pk.h[1] = (_Float16)v.y;
            pk.h[2] = (_Float16)v.z; pk.h[3] = (_Float16)v.w;
            *(uint2*)(Ab + ((row * 640 + k4 * 8) ^ ((row & 7) << 4))) = pk.u;
        }
        __syncthreads();

        f32x4 acc[2][4];
        #pragma unroll
        for (int mt = 0; mt < 2; ++mt)
            #pragma unroll
            for (int tt = 0; tt < 4; ++tt)
                acc[mt][tt] = (f32x4){0.f, 0.f, 0.f, 0.f};

        #pragma unroll
        for (int mt = 0; mt < 2; ++mt) {
            const int arow = mt * 16 + p16;
            #pragma unroll
            for (int ks = 0; ks < 10; ++ks) {
                half8 af = *(const half8*)(Ab + ((arow * 640 + ks * 64 + gq * 16)
                                                 ^ ((arow & 7) << 4)));
                #pragma unroll
                for (int tt = 0; tt < 4; ++tt)
                    acc[mt][tt] = __builtin_amdgcn_mfma_f32_16x16x32_f16(
                        af, bf[tt][ks], acc[mt][tt], 0, 0, 0);
            }
        }

        // store: row = r0 + mt*16 + gq*4 + r ; col = wv*64 + tt*16 + p16
        #pragma unroll
        for (int mt = 0; mt < 2; ++mt)
            #pragma unroll
            for (int tt = 0; tt < 4; ++tt)
                #pragma unroll
                for (int r = 0; r < 4; ++r) {
                    int row = r0 + mt * 16 + gq * 4 + r;
                    if (row < Vv)
                        P[(size_t)row * G4 + wv * 64 + tt * 16 + p16] = acc[mt][tt][r];
                }
        __syncthreads();   // A-tile reads done before restage
    }
}

// ---------------------------------------------------------------------------
// Phase 2: sequential LSTM, two phase-shifted teams per block.
// 64 blocks x 512 thr (8 waves): team = wv>>2 (4 waves each), 2 rows per team.
// Interval i (0..2*Tt): team does MFMA(z=h@Wh) when (i&1)==team, LN/cell when
// (i&1)!=team (step (i-1)>>1). Teams share barriers but run on opposite
// phases, overlapping MFMA/VALU of one with LDS/VALU of the other.
//  - Wh f16 B-frags in VGPRs per wave (gate = wv&3)
//  - z staged in [cb][r][w^swz] layout: conflict-free write2 stores, b128 reads
//  - gate-LN via 16-lane DPP reduce; cell-LN via pure-DPP red64b (no LDS)
//  - P[x[row,t]] contribution prefetched during the team's MFMA interval
// ---------------------------------------------------------------------------
#define TROWS 2
#define LBLK  (Bb / (2 * TROWS))   // 64 blocks

__global__ __launch_bounds__(512, 2) void lstm_mfma2(
    const float* __restrict__ P,       // [V, 4H]
    const float* __restrict__ W,       // [E+H, 4H]
    const int*   __restrict__ x,       // [B, T]
    const float* __restrict__ gains,   // [5, H]
    const float* __restrict__ shifts,  // [5, H]
    float* __restrict__ out)           // [B, T, H]
{
    __shared__ __align__(16) float    z_all[2][2048];     // 16 KB  [team]
    __shared__ __align__(16) float    zn_all[4][4][Hh];   // 8 KB   [team*2+twv]
    __shared__ __align__(16) _Float16 h_all[2][16][Hh];   // 8 KB   [team]

    const int tid  = threadIdx.x;
    const int wv8  = tid >> 6;
    const int team = wv8 >> 2;
    const int twv  = wv8 & 3;          // gate in MFMA phase; row in LN phase
    const int lane = tid & 63;
    const int gq   = lane >> 4;
    const int p16  = lane & 15;
    const int col8 = lane * 8;         // gq*128 + p16*8
    const int bb   = blockIdx.x;

    // zero h (rows >= TROWS stay zero forever)
    {
        uint* hz = (uint*)h_all;
        #pragma unroll
        for (int i = 0; i < 4; ++i) hz[tid + 512 * i] = 0u;
    }

    // Wh B-fragments for gate twv
    half8 bfrag[8][4];
    #pragma unroll
    for (int tt = 0; tt < 8; ++tt) {
        #pragma unroll
        for (int ks = 0; ks < 4; ++ks) {
            half8 h;
            #pragma unroll
            for (int j = 0; j < 8; ++j) {
                h[j] = (_Float16)W[(size_t)(Ee + ks * 32 + gq * 8 + j) * G4
                                   + twv * 128 + tt * 16 + p16];
            }
            bfrag[tt][ks] = h;
        }
    }

    // LN params
    const float4 g_a = *(const float4*)&gains[col8];
    const float4 g_b = *(const float4*)&gains[col8 + 4];
    const float4 s_a = *(const float4*)&shifts[col8];
    const float4 s_b = *(const float4*)&shifts[col8 + 4];
    const float2 gcell = *(const float2*)&gains[4 * Hh + 2 * lane];
    const float2 scell = *(const float2*)&shifts[4 * Hh + 2 * lane];

    const bool lnw   = (twv < TROWS);            // this wave has an LN/cell row
    const int  lrow  = twv;                      // team-local row
    const int  row_g = bb * (2 * TROWS) + team * TROWS + twv;
    const int* xrow  = x + (size_t)row_g * Tt;

    float c0 = 0.f, c1 = 0.f;
    float4 pc0 = {0,0,0,0}, pc1 = {0,0,0,0};
    int tokr = lnw ? xrow[0] : 0;

    char*  const hb  = (char*)&h_all[team][0][0];
    float* const zt  = &z_all[team][0];
    float* const znt = &zn_all[team * 2 + (lnw ? twv : 0)][0][0];

    __syncthreads();

    for (int i = 0; i <= 2 * Tt; ++i) {
        const int  ms   = i >> 1;
        const bool do_m = ((i & 1) == team) && (ms < Tt);
        const int  ls   = (i - 1) >> 1;
        const bool do_l = ((i & 1) != team) && (i >= 1) && (ls < Tt);

        if (do_m) {
            // prefetch P contribution for this team's LN(ms) next interval
            if (lnw) {
                pc0 = *(const float4*)&P[(size_t)tokr * G4 + col8];
                pc1 = *(const float4*)&P[(size_t)tokr * G4 + col8 + 4];
                int nst = (ms + 1 < Tt) ? ms + 1 : Tt - 1;
                tokr = xrow[nst];
            }

            // A-fragments from team h tile
            half8 af[4];
            #pragma unroll
            for (int ks = 0; ks < 4; ++ks) {
                af[ks] = *(const half8*)(hb + p16 * 256
                              + ((ks * 64 + (gq << 4)) ^ ((p16 & 7) << 4)));
            }

            f32x4 acc[8];
            #pragma unroll
            for (int tt = 0; tt < 8; ++tt) acc[tt] = (f32x4){0.f, 0.f, 0.f, 0.f};
            #pragma unroll
            for (int tt = 0; tt < 8; ++tt) {
                #pragma unroll
                for (int ks = 0; ks < 4; ++ks) {
                    acc[tt] = __builtin_amdgcn_mfma_f32_16x16x32_f16(
                        af[ks], bfrag[tt][ks], acc[tt], 0, 0, 0);
                }
            }

            // z stage: [cb][r][w^swz], conflict-free (write2-fusable)
            if (lane < 16) {
                #pragma unroll
                for (int tt = 0; tt < 8; ++tt) {
                    const int cb = twv * 8 + tt;
                    float* zp = zt + cb * 64 + (p16 ^ ((cb & 3) << 2));
                    #pragma unroll
                    for (int r = 0; r < 4; ++r) zp[r * 16] = acc[tt][r];
                }
            }
        }

        if (do_l && lnw) {
            // z read: cols col8..col8+7 of row lrow
            const int cb0  = lane >> 1;
            const int wb   = 8 * (lane & 1);
            const int mxor = (cb0 & 3) << 2;
            const int b1   = wb ^ mxor;
            const float* zp = zt + cb0 * 64 + lrow * 16;
            float4 za = *(const float4*)(zp + b1);        // cols +0..3
            float4 zb = *(const float4*)(zp + (b1 ^ 4));  // cols +4..7

            float zv[8];
            zv[0] = za.x + pc0.x; zv[1] = za.y + pc0.y;
            zv[2] = za.z + pc0.z; zv[3] = za.w + pc0.w;
            zv[4] = zb.x + pc1.x; zv[5] = zb.y + pc1.y;
            zv[6] = zb.z + pc1.z; zv[7] = zb.w + pc1.w;

            // gate-LN over this gate's 128 cols (16 lanes x 8 each)
            float s = 0.f, q = 0.f;
            #pragma unroll
            for (int j = 0; j < 8; ++j) { s += zv[j]; q = fmaf(zv[j], zv[j], q); }
            s = red16(s); q = red16(q);
            {
                const float mean = s * (1.0f / Hh);
                const float var  = q * (1.0f / Hh) - mean * mean;
                const float rstd = rsqrtf(var + EPS);
                const float ga[8] = {g_a.x, g_a.y, g_a.z, g_a.w, g_b.x, g_b.y, g_b.z, g_b.w};
                const float sa[8] = {s_a.x, s_a.y, s_a.z, s_a.w, s_b.x, s_b.y, s_b.z, s_b.w};
                #pragma unroll
                for (int j = 0; j < 8; ++j)
                    zv[j] = (zv[j] - mean) * rstd * ga[j] + sa[j];
            }

            // transpose through per-wave scratch (intra-wave, in-order LDS)
            *(float4*)&znt[gq * Hh + p16 * 8]     = (float4){zv[0], zv[1], zv[2], zv[3]};
            *(float4*)&znt[gq * Hh + p16 * 8 + 4] = (float4){zv[4], zv[5], zv[6], zv[7]};

            float2 iv = *(const float2*)&znt[0 * Hh + 2 * lane];
            float2 jv = *(const float2*)&znt[1 * Hh + 2 * lane];
            float2 fv = *(const float2*)&znt[2 * Hh + 2 * lane];
            float2 ov = *(const float2*)&znt[3 * Hh + 2 * lane];

            // cell update for hdims 2*lane, 2*lane+1
            c0 = c0 * sigm(fv.x + FBIAS) + sigm(iv.x) * fmaxf(jv.x, 0.f);
            c1 = c1 * sigm(fv.y + FBIAS) + sigm(iv.y) * fmaxf(jv.y, 0.f);

            // cell-LN over 128 hdims: pure-DPP wave reduction
            float s2 = red64b(c0 + c1);
            float q2 = red64b(fmaf(c0, c0, c1 * c1));
            const float m2 = s2 * (1.0f / Hh);
            const float v2 = q2 * (1.0f / Hh) - m2 * m2;
            const float r2 = rsqrtf(v2 + EPS);
            const float lc0 = (c0 - m2) * r2 * gcell.x + scell.x;
            const float lc1 = (c1 - m2) * r2 * gcell.y + scell.y;
            const float h0 = fmaxf(lc0, 0.f) * sigm(ov.x);
            const float h1 = fmaxf(lc1, 0.f) * sigm(ov.y);

            // store h (f16, swizzled) + output (f32)
            {
                union { _Float16 hh[2]; uint u; } pk;
                pk.hh[0] = (_Float16)h0; pk.hh[1] = (_Float16)h1;
                *(uint*)(hb + lrow * 256 + ((4 * lane) ^ (lrow << 4))) = pk.u;
            }
            *(float2*)&out[((size_t)row_g * Tt + ls) * Hh + 2 * lane] = (float2){h0, h1};
        }

        lds_barrier();
    }
}

// ---------------------------------------------------------------------------
extern "C" void kernel_launch(void* const* d_in, const int* in_sizes, int n_in,
                              void* d_out, int out_size, void* d_ws, size_t ws_size,
                              hipStream_t stream) {
    const int*   x      = (const int*)d_in[0];
    const float* embed  = (const float*)d_in[1];
    const float* W      = (const float*)d_in[2];
    const float* gains  = (const float*)d_in[3];
    const float* shifts = (const float*)d_in[4];
    float* out = (float*)d_out;

    float* P = (float*)d_ws;   // [V, 4H] = 102.4 MB

    embed_proj_mfma<<<dim3(256), dim3(512), 0, stream>>>(embed, W, P);
    lstm_mfma2<<<dim3(LBLK), dim3(512), 0, stream>>>(P, W, x, gains, shifts, out);
}